// Round 3
// baseline (175.811 us; speedup 1.0000x reference)
//
#include <hip/hip_runtime.h>
#include <hip/hip_bf16.h>

// Colorcal: out[b,c,h,w] = (wcam[cam[b],c] + wident[id[b],c]) * image[b,c,h,w]
//                        + (bcam[cam[b],c] + bident[id[b],c])
// B=32, C=3, H=W=1024, fp32. Streaming op: 768 MB total -> HBM roofline ~128us
// (m13 copy ceiling 6.29 TB/s).

typedef float f32x4 __attribute__((ext_vector_type(4)));  // native vector: OK for nontemporal builtins

#define HW     (1024 * 1024)
#define HW4    (HW / 4)          // float4 per plane = 262144
#define GRIDX  16                // blocks per plane
#define TPB    256
#define STRIDE (GRIDX * TPB)     // 4096 threads per plane
#define ITERS  (HW4 / (STRIDE * 4))  // 16 unroll-4 iterations, exact (no tail)

__global__ __launch_bounds__(256) void colorcal_kernel(
    const float* __restrict__ image,
    const int*   __restrict__ camindex,
    const int*   __restrict__ idindex,
    const float* __restrict__ wcam,
    const float* __restrict__ bcam,
    const float* __restrict__ wident,
    const float* __restrict__ bident,
    float* __restrict__ out)
{
    const int plane = blockIdx.y;          // 0..95 == b*3 + c
    const int b     = plane / 3;
    const int c     = plane - b * 3;

    // Wave-uniform scalar gathers: once per block.
    const int cam = camindex[b];
    const int id  = idindex[b];
    const float w    = wcam[cam * 3 + c] + wident[id * 3 + c];
    const float bias = bcam[cam * 3 + c] + bident[id * 3 + c];

    const size_t planeBase = (size_t)plane * HW;
    const f32x4* __restrict__ in4  = reinterpret_cast<const f32x4*>(image + planeBase);
    f32x4*       __restrict__ out4 = reinterpret_cast<f32x4*>(out + planeBase);

    const int tid = blockIdx.x * TPB + threadIdx.x;

    for (int it = 0; it < ITERS; ++it) {
        const int i0 = it * (STRIDE * 4) + tid;
        // Issue 4 independent coalesced 16B loads before any use -> 4-deep vmcnt.
        f32x4 v0 = __builtin_nontemporal_load(&in4[i0 + 0 * STRIDE]);
        f32x4 v1 = __builtin_nontemporal_load(&in4[i0 + 1 * STRIDE]);
        f32x4 v2 = __builtin_nontemporal_load(&in4[i0 + 2 * STRIDE]);
        f32x4 v3 = __builtin_nontemporal_load(&in4[i0 + 3 * STRIDE]);

        v0 = v0 * w + bias;
        v1 = v1 * w + bias;
        v2 = v2 * w + bias;
        v3 = v3 * w + bias;

        __builtin_nontemporal_store(v0, &out4[i0 + 0 * STRIDE]);
        __builtin_nontemporal_store(v1, &out4[i0 + 1 * STRIDE]);
        __builtin_nontemporal_store(v2, &out4[i0 + 2 * STRIDE]);
        __builtin_nontemporal_store(v3, &out4[i0 + 3 * STRIDE]);
    }
}

extern "C" void kernel_launch(void* const* d_in, const int* in_sizes, int n_in,
                              void* d_out, int out_size, void* d_ws, size_t ws_size,
                              hipStream_t stream) {
    const float* image    = (const float*)d_in[0];
    const int*   camindex = (const int*)  d_in[1];
    const int*   idindex  = (const int*)  d_in[2];
    const float* wcam     = (const float*)d_in[3];
    const float* bcam     = (const float*)d_in[4];
    const float* wident   = (const float*)d_in[5];
    const float* bident   = (const float*)d_in[6];
    float* out = (float*)d_out;

    // 96 planes x 16 blocks = 1536 blocks of 256 = 24 waves/CU (one clean round).
    dim3 grid(GRIDX, 96, 1);
    dim3 block(TPB, 1, 1);
    colorcal_kernel<<<grid, block, 0, stream>>>(
        image, camindex, idindex, wcam, bcam, wident, bident, out);
}